// Round 2
// 14488.118 us; speedup vs baseline: 1.0331x; 1.0331x over previous
//
#include <hip/hip_runtime.h>
#include <stdint.h>

#define T_STEPS 4096
#define BATCH 32
#define HID 512
#define GROUPS 8            // blocks per batch
#define BLK_THREADS 1024    // 16 waves; 256 blocks = exactly 1/CU
#define NBLOCKS 256
#define SLOT_DW (BATCH * GROUPS * 64)  // dwords per parity slot (16384 = 64 KB)

typedef _Float16 h2_t __attribute__((ext_vector_type(2)));
typedef uint32_t u32x8 __attribute__((ext_vector_type(8)));

__device__ inline uint32_t pack_h2(float a, float b) {
  h2_t v;
  v.x = (_Float16)a;
  v.y = (_Float16)b;
  return __builtin_bit_cast(uint32_t, v);
}

__device__ inline float fdot2(uint32_t a, uint32_t b, float c) {
  return __builtin_amdgcn_fdot2(__builtin_bit_cast(h2_t, a),
                                __builtin_bit_cast(h2_t, b), c, false);
}

// AGPR-resident weight read (unified RF; proven earlier rounds: FETCH_SIZE
// ~95 MB == one-time traffic only, no per-step weight re-fetch).
__device__ inline uint32_t aread(uint32_t a) {
  uint32_t v;
  asm("v_accvgpr_read_b32 %0, %1" : "=v"(v) : "a"(a));
  return v;
}

// Launder a wave-uniform pointer into an SGPR-resident uint64 so the "s"
// inline-asm constraint can bind it.
__device__ inline uint64_t uni64(const void* p) {
  uint32_t lo = __builtin_amdgcn_readfirstlane((uint32_t)(uintptr_t)p);
  uint32_t hi = __builtin_amdgcn_readfirstlane((uint32_t)((uintptr_t)p >> 32));
  return ((uint64_t)hi << 32) | lo;
}

// Scalar K$ invalidate: next s_load misses K$ -> served fresh from the XCD's
// L2 (same-XCD guaranteed by the claim protocol). sc0 VECTOR loads do NOT
// bypass vL1 on gfx950 (round-6/7 finding), so the scalar path stays the
// coherent communication path.
__device__ inline void kinv() {
  asm volatile("s_dcache_inv" ::: "memory");
}

// Round-11 fetch: exactly the 36 useful dwords of the record (32 data + 4
// tags), 8 scalar loads issued back-to-back, ONE lgkmcnt(0) => one parallel
// L2 round trip. 36 output SGPRs (vs round-10's 64-SGPR x16 quad, the
// suspected allocator-killer). Consumers of the outputs have true data
// dependence on this asm (waitcnt inside), so they cannot be hoisted above
// completion.
__device__ inline void sload_rec(uint64_t p, u32x8* d0, u32x8* d1,
                                 u32x8* d2, u32x8* d3,
                                 uint32_t* t0, uint32_t* t1,
                                 uint32_t* t2, uint32_t* t3) {
  asm volatile("s_load_dwordx8 %0, %8, 0x0\n\t"
               "s_load_dword %4, %8, 0x20\n\t"
               "s_load_dwordx8 %1, %8, 0x40\n\t"
               "s_load_dword %5, %8, 0x60\n\t"
               "s_load_dwordx8 %2, %8, 0x80\n\t"
               "s_load_dword %6, %8, 0xa0\n\t"
               "s_load_dwordx8 %3, %8, 0xc0\n\t"
               "s_load_dword %7, %8, 0xe0\n\t"
               "s_waitcnt lgkmcnt(0)"
               : "=&s"(*d0), "=&s"(*d1), "=&s"(*d2), "=&s"(*d3),
                 "=&s"(*t0), "=&s"(*t1), "=&s"(*t2), "=&s"(*t3)
               : "s"(p) : "memory");
}

__device__ inline float sigf(float x) { return 1.0f / (1.0f + __expf(-x)); }
__device__ inline float tanh_fast(float x) {
  float a = fabsf(x);
  float e = __expf(-2.0f * a);
  float r = (1.0f - e) / (1.0f + e);
  return copysignf(r, x);
}

// Tagged-line publish protocol (round 10 design, round 11 hardening).
//
// Record per (slot, batch, group): 4 cache lines of 16 dwords each.
//   line L: dwords 0..7  = packed f16x2 h values (record dwords 8L..8L+7)
//           dword  8     = step tag
//           dwords 9..15 = pad
// The tag lives in the SAME 64B line as the data it certifies; each line is
// covered by a single predicated wave store -> one masked L2 write
// transaction per line -> tag visibility implies data visibility. This
// removes the producer's vmcnt(0) drain AND the separate counter store, and
// collapses the consumer's detect+fetch into one L2 round trip.
//
// Overwrite safety (parity double-buffer, unchanged from round 9): a block
// publishes tag t+2 into slot[t&1] only after passing its step-t+1 barrier,
// which requires all its waves to have seen every group's tag t+1 — and a
// group publishes tag t+1 only after ALL its own waves consumed slot[t&1]
// (consume precedes its barrier precedes its publish). Tags are unique
// (<= 4096), so no ABA.
__global__ __launch_bounds__(BLK_THREADS)
void lstm_tagline(const float* __restrict__ x0,
                  const float* __restrict__ W_ih,
                  const float* __restrict__ W_hh,
                  const float* __restrict__ b_ih,
                  const float* __restrict__ b_hh,
                  const float* __restrict__ W_lin,
                  const float* __restrict__ b_lin,
                  float* __restrict__ y,
                  uint32_t* __restrict__ h_ex,   // [2][BATCH][GROUPS][64]
                  int* __restrict__ claim)       // [8][16] per-XCD claim ctrs
{
  __shared__ float x0_lds[T_STEPS];     // 16 KB: this batch's x0 column
  __shared__ float ylds[T_STEPS];       // 16 KB: per-block y partials
  __shared__ float gacc[2][256];        // parity-buffered gate accumulators
  __shared__ int s_bg;

  const int tid = threadIdx.x;

  // ---- claim a (batch, group) slot on THIS block's physical XCD ----
  if (tid == 0) {
    uint32_t xcc;
    asm volatile("s_getreg_b32 %0, hwreg(HW_REG_XCC_ID)" : "=s"(xcc));
    xcc &= 7;
    int slot = atomicAdd(claim + xcc * 16, 1);   // agent-scope, one-time
    s_bg = (slot < 32) ? (int)(((4 * xcc + (slot >> 3)) << 3) | (slot & 7))
                       : -1;
  }
  __syncthreads();
  if (s_bg < 0) return;                  // surplus block
  const int b  = s_bg >> 3;              // batch (same XCD for all 8 groups)
  const int g  = s_bg & 7;               // group within batch
  const int u0 = g * 64;                 // first hidden unit owned
  const int wv = tid >> 6;               // wave 0..15
  const int rg = wv >> 3;                // row-group 0..1
  const int cs = wv & 7;                 // col-slice 0..7 == producer group
  const int l  = tid & 63;

  // ---- one-time: W_hh slice -> packed f16x2 -> AGPRs ----
  uint32_t a0[32], a1[32];
  {
    const int r0 = 128 * rg + l;
    const int r1 = r0 + 64;
    const int R0 = (r0 >> 6) * HID + u0 + (r0 & 63);  // gate*512 + unit
    const int R1 = (r1 >> 6) * HID + u0 + (r1 & 63);
    const float2* p0 = (const float2*)(W_hh + (size_t)R0 * HID + 64 * cs);
    const float2* p1 = (const float2*)(W_hh + (size_t)R1 * HID + 64 * cs);
#pragma unroll
    for (int k = 0; k < 32; ++k) {
      float2 a = p0[k], c = p1[k];
      uint32_t t0 = pack_h2(a.x, a.y);
      uint32_t t1 = pack_h2(c.x, c.y);
      asm("v_accvgpr_write_b32 %0, %1" : "=a"(a0[k]) : "v"(t0));
      asm("v_accvgpr_write_b32 %0, %1" : "=a"(a1[k]) : "v"(t1));
    }
  }
  // ---- one-time: x0 column, y partials, gacc ----
  for (int i = tid; i < T_STEPS; i += BLK_THREADS) {
    x0_lds[i] = x0[i * BATCH + b];
    ylds[i] = 0.f;
  }
  if (tid < 256) { gacc[0][tid] = 0.f; gacc[1][tid] = 0.f; }

  // ---- activation-lane constants (lanes 0..63 of wave 0) ----
  float c_state = 0.f;
  float wih_[4] = {0.f, 0.f, 0.f, 0.f}, bs_[4] = {0.f, 0.f, 0.f, 0.f};
  float wlin_u = 0.f, blin = 0.f;
  if (tid < 64) {
#pragma unroll
    for (int j = 0; j < 4; ++j) {
      int R = j * HID + u0 + tid;
      wih_[j] = W_ih[R];
      bs_[j] = b_ih[R] + b_hh[R];
    }
    wlin_u = W_lin[u0 + tid];
    blin = b_lin[0];
  }

  // ---- wave-uniform SGPR addresses ----
  uint32_t* hb = h_ex + (size_t)b * (GROUPS * 64);   // 512 dwords / batch
  const uint64_t dpu[2] = { uni64(hb + 64 * cs),
                            uni64(hb + SLOT_DW + 64 * cs) };
  uint32_t* pub01[2] = { hb + 64 * g, hb + SLOT_DW + 64 * g };

  __syncthreads();

  int dead = 0;
  for (int t = 0; t < T_STEPS; ++t) {
    const int sl = t & 1, ns = sl ^ 1;

    // ---- fused poll+fetch: inv; load 4 tagged lines; check 4 tags ----
    u32x8 D0, D1, D2, D3;
    uint32_t tg0, tg1, tg2, tg3;
    {
      const uint32_t want = (uint32_t)t;
      int guard = 0;
      for (;;) {
        kinv();                              // certifies BOTH tag and data
        sload_rec(dpu[sl], &D0, &D1, &D2, &D3, &tg0, &tg1, &tg2, &tg3);
        if ((tg0 == want) & (tg1 == want) &
            (tg2 == want) & (tg3 == want)) break;
        if (dead || ++guard > (1 << 18)) { dead = 1; break; }  // anti-hang
        __builtin_amdgcn_s_sleep(1);
      }
    }

    // ---- matvec: 2 rows x 64 cols per lane; h uniform from SGPRs ----
    // 4 independent accumulator chains to hide v_dot2 latency.
    float acc0a = 0.f, acc0b = 0.f, acc1a = 0.f, acc1b = 0.f;
#pragma unroll
    for (int k = 0; k < 8; ++k) {
      acc0a = fdot2(aread(a0[k]),      D0[k], acc0a);
      acc1a = fdot2(aread(a1[k]),      D0[k], acc1a);
      acc0b = fdot2(aread(a0[8 + k]),  D1[k], acc0b);
      acc1b = fdot2(aread(a1[8 + k]),  D1[k], acc1b);
      acc0a = fdot2(aread(a0[16 + k]), D2[k], acc0a);
      acc1a = fdot2(aread(a1[16 + k]), D2[k], acc1a);
      acc0b = fdot2(aread(a0[24 + k]), D3[k], acc0b);
      acc1b = fdot2(aread(a1[24 + k]), D3[k], acc1b);
    }
    atomicAdd(&gacc[sl][128 * rg + l], acc0a + acc0b);      // conflict-free
    atomicAdd(&gacc[sl][128 * rg + 64 + l], acc1a + acc1b);
    __syncthreads();   // the ONE block barrier per step

    // ---- activations + publish (wave 0, 64 lanes = 64 owned units) ----
    if (tid < 64) {
      const float xv = x0_lds[t];
      float gi = gacc[sl][tid]       + xv * wih_[0] + bs_[0];
      float gf = gacc[sl][tid + 64]  + xv * wih_[1] + bs_[1];
      float gg = gacc[sl][tid + 128] + xv * wih_[2] + bs_[2];
      float go = gacc[sl][tid + 192] + xv * wih_[3] + bs_[3];
      float si = sigf(gi), sf = sigf(gf), tg_ = tanh_fast(gg), so = sigf(go);
      c_state = sf * c_state + si * tg_;
      float h = so * tanh_fast(c_state);

      // publish: 36-lane predicated store writes 4 self-certifying lines.
      //   even lanes: record dword j=tid/2 at line j>>3, slot j&7
      //   lanes 1,3,5,7: tag dword (t+1) at line (tid-1)/2, slot 8
      // NO vmcnt drain, NO separate counter store.
      float hn = __shfl_down(h, 1, 64);
      uint32_t val = 0;
      int doff = 0;
      bool act = false;
      if ((tid & 1) == 0) {
        int j = tid >> 1;
        val = pack_h2(h, hn);
        doff = ((j >> 3) << 4) + (j & 7);
        act = true;
      } else if (tid < 8) {
        int L = (tid - 1) >> 1;
        val = (uint32_t)(t + 1);
        doff = (L << 4) + 8;
        act = true;
      }
      if (act) pub01[ns][doff] = val;

      // recycle gacc[sl] for step t+2 (safe: program order + next barrier)
      gacc[sl][tid] = 0.f;
      gacc[sl][tid + 64] = 0.f;
      gacc[sl][tid + 128] = 0.f;
      gacc[sl][tid + 192] = 0.f;

      // y partial (off critical path): fold 64 units -> ylds[t]
      float p = wlin_u * h;
#pragma unroll
      for (int m = 32; m >= 1; m >>= 1) p += __shfl_xor(p, m, 64);
      if (tid == 0) ylds[t] = p;
    }
  }

  // ---- drain: block partials -> global y (g==0 adds bias + residual) ----
  __syncthreads();
  for (int i = tid; i < T_STEPS; i += BLK_THREADS) {
    float val = ylds[i];
    if (g == 0) val += blin + x0_lds[i];
    unsafeAtomicAdd(&y[i * BATCH + b], val);
  }
}

extern "C" void kernel_launch(void* const* d_in, const int* in_sizes, int n_in,
                              void* d_out, int out_size, void* d_ws, size_t ws_size,
                              hipStream_t stream) {
  const float* x0    = (const float*)d_in[0];
  const float* W_ih  = (const float*)d_in[1];
  const float* W_hh  = (const float*)d_in[2];
  const float* b_ih  = (const float*)d_in[3];
  const float* b_hh  = (const float*)d_in[4];
  const float* W_lin = (const float*)d_in[5];
  const float* b_lin = (const float*)d_in[6];
  float* y = (float*)d_out;

  uint32_t* h_ex = (uint32_t*)d_ws;                    // 2 x 64 KB slots
  int* claim     = (int*)(h_ex + 2 * SLOT_DW);         // 512 B
  const size_t init_bytes = (size_t)2 * SLOT_DW * sizeof(uint32_t)
                            + 8 * 16 * sizeof(int);

  // memset 0: slot-0 tags = 0 with h = 0 (== "h_0 available"), claim = 0
  (void)hipMemsetAsync(d_ws, 0, init_bytes, stream);
  (void)hipMemsetAsync(d_out, 0, (size_t)out_size * sizeof(float), stream);

  hipLaunchKernelGGL(lstm_tagline, dim3(NBLOCKS), dim3(BLK_THREADS), 0, stream,
                     x0, W_ih, W_hh, b_ih, b_hh, W_lin, b_lin, y, h_ex, claim);
}